// Round 1
// baseline (621.518 us; speedup 1.0000x reference)
//
#include <hip/hip_runtime.h>
#include <stdint.h>

#define IDIM 2048
#define ODIM 1024
#define NACT 64
#define NB 1024
#define NT 16

typedef __attribute__((ext_vector_type(8))) short short8;
typedef __attribute__((ext_vector_type(4))) float floatx4;

__device__ __forceinline__ unsigned short f2bf(float f) {
    union { float f; unsigned u; } v; v.f = f;
    unsigned r = v.u + 0x7FFFu + ((v.u >> 16) & 1u);
    return (unsigned short)(r >> 16);
}

// ---- temporal mean over T, output bf16 ----
__global__ __launch_bounds__(256) void k_avg(const float* __restrict__ p,
                                             const float* __restrict__ e,
                                             unsigned short* __restrict__ pavg,
                                             unsigned short* __restrict__ eavg) {
    int idx = blockIdx.x * 256 + threadIdx.x;   // 0 .. NB*IDIM/4-1
    int b  = idx >> 9;                          // IDIM/4 = 512 float4 per row
    int d4 = idx & 511;
    const float4* pr = (const float4*)(p + (size_t)b * (NT * IDIM)) + d4;
    const float4* er = (const float4*)(e + (size_t)b * (NT * IDIM)) + d4;
    float sx=0, sy=0, sz=0, sw=0, tx=0, ty=0, tz=0, tw=0;
#pragma unroll
    for (int t = 0; t < NT; ++t) {
        float4 a = pr[t * (IDIM/4)];
        float4 c = er[t * (IDIM/4)];
        sx += a.x; sy += a.y; sz += a.z; sw += a.w;
        tx += c.x; ty += c.y; tz += c.z; tw += c.w;
    }
    const float s = 1.0f / NT;
    ushort4 op = make_ushort4(f2bf(sx*s), f2bf(sy*s), f2bf(sz*s), f2bf(sw*s));
    ushort4 oe = make_ushort4(f2bf(tx*s), f2bf(ty*s), f2bf(tz*s), f2bf(tw*s));
    *(ushort4*)(pavg + (size_t)b*IDIM + d4*4) = op;
    *(ushort4*)(eavg + (size_t)b*IDIM + d4*4) = oe;
}

// ---- f32 -> bf16 convert (for Wp/We) ----
__global__ __launch_bounds__(256) void k_cvt(const float* __restrict__ w,
                                             unsigned short* __restrict__ o) {
    int idx = blockIdx.x * 256 + threadIdx.x;   // over float4s
    float4 v = ((const float4*)w)[idx];
    *(ushort4*)(o + (size_t)idx*4) = make_ushort4(f2bf(v.x), f2bf(v.y), f2bf(v.z), f2bf(v.w));
}

// ---- bucket batch rows by action ----
__global__ void k_group(const int* __restrict__ action,
                        int* __restrict__ order, int* __restrict__ starts) {
    __shared__ int cnt[NACT], cnt2[NACT], base[NACT];
    int t = threadIdx.x;
    if (t < NACT) { cnt[t] = 0; cnt2[t] = 0; }
    __syncthreads();
    int a = action[t];
    atomicAdd(&cnt[a], 1);
    __syncthreads();
    if (t < NACT) {
        int s = 0;
        for (int j = 0; j < t; ++j) s += cnt[j];
        base[t] = s;
        starts[t] = s;
        if (t == NACT - 1) starts[NACT] = s + cnt[t];
    }
    __syncthreads();
    int pos = base[a] + atomicAdd(&cnt2[a], 1);
    order[pos] = t;
}

// ---- embed GEMM: C[b][d] = sum_k avg[b][k]*W[d][k] + bias[d] ----
// tiles: BM=128, BN=64, BK=32; block=256 (4 waves); wave w: rows [w*32,w*32+32), all 64 cols
__global__ __launch_bounds__(256) void k_embed(const unsigned short* __restrict__ pavg,
                                               const unsigned short* __restrict__ eavg,
                                               const unsigned short* __restrict__ wpb,
                                               const unsigned short* __restrict__ web,
                                               const float* __restrict__ bp,
                                               const float* __restrict__ be,
                                               unsigned short* __restrict__ peb,
                                               float* __restrict__ eout) {
    const int z = blockIdx.z;
    const unsigned short* Ag = z ? eavg : pavg;
    const unsigned short* Wg = z ? web  : wpb;
    const float* bias        = z ? be   : bp;
    const int row0 = blockIdx.x * 128;
    const int col0 = blockIdx.y * 64;
    __shared__ unsigned short As[128*40];  // rows padded to 40 bf16 (80B)
    __shared__ unsigned short Bs[64*40];
    const int tid  = threadIdx.x;
    const int w    = tid >> 6, lane = tid & 63;
    const int lr   = lane & 15, quad = lane >> 4;
    floatx4 acc[2][4];
#pragma unroll
    for (int s = 0; s < 2; ++s)
#pragma unroll
        for (int t = 0; t < 4; ++t) { floatx4 zz = {0.f,0.f,0.f,0.f}; acc[s][t] = zz; }

    const int rA0 = tid >> 2,        pA0 = tid & 3;          // chunk tid
    const int rA1 = (tid+256) >> 2,  pA1 = tid & 3;          // chunk tid+256

    for (int ks = 0; ks < IDIM/32; ++ks) {
        const int k0 = ks * 32;
        int4 a0 = *(const int4*)(Ag + (size_t)(row0 + rA0)*IDIM + k0 + pA0*8);
        int4 a1 = *(const int4*)(Ag + (size_t)(row0 + rA1)*IDIM + k0 + pA1*8);
        int4 b0 = *(const int4*)(Wg + (size_t)(col0 + rA0)*IDIM + k0 + pA0*8);
        __syncthreads();
        *(int4*)(&As[rA0*40 + pA0*8]) = a0;
        *(int4*)(&As[rA1*40 + pA1*8]) = a1;
        *(int4*)(&Bs[rA0*40 + pA0*8]) = b0;
        __syncthreads();
        short8 af[2], bf[4];
#pragma unroll
        for (int s = 0; s < 2; ++s)
            af[s] = *(const short8*)&As[(w*32 + s*16 + lr)*40 + quad*8];
#pragma unroll
        for (int t = 0; t < 4; ++t)
            bf[t] = *(const short8*)&Bs[(t*16 + lr)*40 + quad*8];
#pragma unroll
        for (int s = 0; s < 2; ++s)
#pragma unroll
            for (int t = 0; t < 4; ++t)
                acc[s][t] = __builtin_amdgcn_mfma_f32_16x16x32_bf16(af[s], bf[t], acc[s][t], 0, 0, 0);
    }

#pragma unroll
    for (int s = 0; s < 2; ++s) {
        const int rg = row0 + w*32 + s*16 + quad*4;
#pragma unroll
        for (int t = 0; t < 4; ++t) {
            const int cg = col0 + t*16 + lr;
            const float bv = bias[cg];
#pragma unroll
            for (int r = 0; r < 4; ++r) {
                float val = acc[s][t][r] + bv;
                if (z) eout[(size_t)(rg + r)*ODIM + cg] = val;
                else   peb[(size_t)(rg + r)*ODIM + cg] = f2bf(val);
            }
        }
    }
}

// ---- grouped transform: p_t[b][i] = sum_j Wt[a][i][j] * p_embed[b][j] ----
// grid: (ODIM/128 i-tiles, 32 chunk slots, 64 actions); chunk = up to 32 b rows
__global__ __launch_bounds__(256) void k_trans(const float* __restrict__ Wt,
                                               const unsigned short* __restrict__ peb,
                                               const int* __restrict__ order,
                                               const int* __restrict__ starts,
                                               float* __restrict__ out) {
    const int a  = blockIdx.z;
    const int g0 = starts[a], g1 = starts[a+1];
    const int gs = g0 + blockIdx.y * 32;
    int nb = g1 - gs;
    if (nb <= 0) return;
    if (nb > 32) nb = 32;
    const int i0 = blockIdx.x * 128;
    const float* M = Wt + (size_t)a * ODIM * ODIM;
    __shared__ unsigned short Ms[128*40];
    __shared__ unsigned short Ps[32*40];
    __shared__ int sorder[32];
    const int tid = threadIdx.x;
    if (tid < 32) sorder[tid] = order[gs + (tid < nb ? tid : 0)];
    __syncthreads();
    const int w  = tid >> 6, lane = tid & 63;
    const int lr = lane & 15, quad = lane >> 4;
    const int prw = sorder[(tid >> 2) & 31];      // P-staging source row (tid<128 uses it)
    floatx4 acc[2][2];
#pragma unroll
    for (int s = 0; s < 2; ++s)
#pragma unroll
        for (int t = 0; t < 2; ++t) { floatx4 zz = {0.f,0.f,0.f,0.f}; acc[s][t] = zz; }

    for (int ks = 0; ks < ODIM/32; ++ks) {
        const int k0 = ks * 32;
        float4 mv[4];
#pragma unroll
        for (int u = 0; u < 4; ++u) {
            int c = tid + u*256;
            int r = c >> 3, pt = c & 7;
            mv[u] = *(const float4*)(M + (size_t)(i0 + r)*ODIM + k0 + pt*4);
        }
        int4 pv;
        if (tid < 128) {
            int pt = tid & 3;
            pv = *(const int4*)(peb + (size_t)prw*ODIM + k0 + pt*8);
        }
        __syncthreads();
#pragma unroll
        for (int u = 0; u < 4; ++u) {
            int c = tid + u*256;
            int r = c >> 3, pt = c & 7;
            *(ushort4*)(&Ms[r*40 + pt*4]) =
                make_ushort4(f2bf(mv[u].x), f2bf(mv[u].y), f2bf(mv[u].z), f2bf(mv[u].w));
        }
        if (tid < 128) {
            int r = tid >> 2, pt = tid & 3;
            *(int4*)(&Ps[r*40 + pt*8]) = pv;
        }
        __syncthreads();
        short8 af[2], bf[2];
#pragma unroll
        for (int s = 0; s < 2; ++s)
            af[s] = *(const short8*)&Ms[(w*32 + s*16 + lr)*40 + quad*8];
#pragma unroll
        for (int t = 0; t < 2; ++t)
            bf[t] = *(const short8*)&Ps[(t*16 + lr)*40 + quad*8];
#pragma unroll
        for (int s = 0; s < 2; ++s)
#pragma unroll
            for (int t = 0; t < 2; ++t)
                acc[s][t] = __builtin_amdgcn_mfma_f32_16x16x32_bf16(af[s], bf[t], acc[s][t], 0, 0, 0);
    }

#pragma unroll
    for (int t = 0; t < 2; ++t) {
        int bb = t*16 + lr;
        if (bb < nb) {
            int bg = sorder[bb];
#pragma unroll
            for (int s = 0; s < 2; ++s) {
                int ig = i0 + w*32 + s*16 + quad*4;   // 4 acc regs = consecutive i
                float4 v = make_float4(acc[s][t][0], acc[s][t][1], acc[s][t][2], acc[s][t][3]);
                *(float4*)(out + (size_t)bg*ODIM + ig) = v;
            }
        }
    }
}

extern "C" void kernel_launch(void* const* d_in, const int* in_sizes, int n_in,
                              void* d_out, int out_size, void* d_ws, size_t ws_size,
                              hipStream_t stream) {
    const float* prec = (const float*)d_in[0];
    const float* eff  = (const float*)d_in[1];
    const int*   act  = (const int*)d_in[2];
    const float* Wp   = (const float*)d_in[3];
    const float* bp   = (const float*)d_in[4];
    const float* We   = (const float*)d_in[5];
    const float* be   = (const float*)d_in[6];
    const float* Wt   = (const float*)d_in[7];
    float* out = (float*)d_out;                // [0,1048576): p_transformed, then e_embed

    uint8_t* ws = (uint8_t*)d_ws;              // needs ~18.9 MB
    unsigned short* pavg = (unsigned short*)(ws + 0);
    unsigned short* eavg = (unsigned short*)(ws + 4194304);
    unsigned short* wpb  = (unsigned short*)(ws + 8388608);
    unsigned short* web  = (unsigned short*)(ws + 12582912);
    unsigned short* peb  = (unsigned short*)(ws + 16777216);
    int* order  = (int*)(ws + 18874368);
    int* starts = order + NB;

    hipLaunchKernelGGL(k_avg,   dim3(2048),     dim3(256),  0, stream, prec, eff, pavg, eavg);
    hipLaunchKernelGGL(k_cvt,   dim3(2048),     dim3(256),  0, stream, Wp, wpb);
    hipLaunchKernelGGL(k_cvt,   dim3(2048),     dim3(256),  0, stream, We, web);
    hipLaunchKernelGGL(k_group, dim3(1),        dim3(1024), 0, stream, act, order, starts);
    hipLaunchKernelGGL(k_embed, dim3(8,16,2),   dim3(256),  0, stream,
                       pavg, eavg, wpb, web, bp, be, peb, out + 1048576);
    hipLaunchKernelGGL(k_trans, dim3(8,32,64),  dim3(256),  0, stream,
                       Wt, peb, order, starts, out);
}